// Round 10
// baseline (480.226 us; speedup 1.0000x reference)
//
#include <hip/hip_runtime.h>
#include <hip/hip_cooperative_groups.h>

namespace cg = cooperative_groups;

#define L2E 1.44269504088896340736f
#define LN2 0.69314718055994530942f
#define NEGB -1e30f

typedef float f32x4 __attribute__((ext_vector_type(4)));
typedef __bf16 bf16x8 __attribute__((ext_vector_type(8)));

// workspace layout (bytes)
static constexpr size_t WT_ALL_OFF   = 0;        // 80*768 bf16
static constexpr size_t WT_TYPE_OFF  = 122880;   // 512*768 bf16 (rows 500..511 zero)
static constexpr size_t EM_T_OFF     = 909312;   // 512*3*64 f32 (em_t[s][j][b])
static constexpr size_t SCORES_OFF   = 1302528;  // 64*512 f32
static constexpr size_t LABELS_T_OFF = 1433600;  // 512*64 i32
static constexpr size_t LEN_OFF      = 1564672;  // 64 i32
static constexpr size_t MATM_OFF     = 3400192;  // 64*9*64 f32
static constexpr size_t PSC_OFF      = 3547648;  // 64*64 f32
static constexpr size_t PQ_OFF       = 3564032;  // 512 rows * 4 quarters * 4 f32
static constexpr size_t VL_OFF       = 3596800;  // 512 f32

__device__ __forceinline__ unsigned short f2bf(float f) {
  unsigned u = __builtin_bit_cast(unsigned, f);
  u += 0x7FFFu + ((u >> 16) & 1u);
  return (unsigned short)(u >> 16);
}
__device__ __forceinline__ float sel3(float a, float b, float c, int i) {
  return i == 0 ? a : (i == 1 ? b : c);
}
__device__ __forceinline__ float lse3(float x, float y, float z) {
  float m = fmaxf(fmaxf(x, y), z);
  float p = exp2f((x - m) * L2E) + exp2f((y - m) * L2E) + exp2f((z - m) * L2E);
  return m + log2f(p) * LN2;
}
__device__ __forceinline__ bf16x8 pack8(float4 lo, float4 hi) {
  union { unsigned u[4]; bf16x8 v; } r;
  asm("v_cvt_pk_bf16_f32 %0, %1, %2" : "=v"(r.u[0]) : "v"(lo.x), "v"(lo.y));
  asm("v_cvt_pk_bf16_f32 %0, %1, %2" : "=v"(r.u[1]) : "v"(lo.z), "v"(lo.w));
  asm("v_cvt_pk_bf16_f32 %0, %1, %2" : "=v"(r.u[2]) : "v"(hi.x), "v"(hi.y));
  asm("v_cvt_pk_bf16_f32 %0, %1, %2" : "=v"(r.u[3]) : "v"(hi.z), "v"(hi.w));
  return r.v;
}
__device__ __forceinline__ void gload_lds16(const void* g, void* l) {
  __builtin_amdgcn_global_load_lds(
      (const __attribute__((address_space(1))) unsigned*)g,
      (__attribute__((address_space(3))) unsigned*)l, 16, 0, 0);
}

__global__ __launch_bounds__(256, 2) void mega(
    const float* __restrict__ hidden, const int* __restrict__ amask,
    const int* __restrict__ plab, const int* __restrict__ tlab,
    const int* __restrict__ tpos, const float* __restrict__ biw,
    const float* __restrict__ Wpos, const float* __restrict__ bpos,
    const float* __restrict__ strans, const float* __restrict__ etrans,
    const float* __restrict__ trans, const float* __restrict__ W1,
    const float* __restrict__ b1, const float* __restrict__ W2,
    const float* __restrict__ b2, const float* __restrict__ Wtype,
    const float* __restrict__ btype, char* __restrict__ ws,
    float* __restrict__ out) {
  __shared__ __align__(16) char smem[65536];
  cg::grid_group grid = cg::this_grid();
  const int bid = blockIdx.x, t = threadIdx.x, w = t >> 6, l = t & 63;

  unsigned short* wt_all   = (unsigned short*)(ws + WT_ALL_OFF);
  unsigned short* wt_type  = (unsigned short*)(ws + WT_TYPE_OFF);
  float* em_t     = (float*)(ws + EM_T_OFF);
  float* scores   = (float*)(ws + SCORES_OFF);
  int*   labels_t = (int*)(ws + LABELS_T_OFF);
  int*   lengths  = (int*)(ws + LEN_OFF);
  float* matM     = (float*)(ws + MATM_OFF);
  float* psc      = (float*)(ws + PSC_OFF);
  float* pq       = (float*)(ws + PQ_OFF);
  float* vlbuf    = (float*)(ws + VL_OFF);

  // ================= P0: weight prep + lengths =================
  if (bid < 108) {
    float (*tl)[65] = (float(*)[65])smem;
    const bool is_type = bid < 96;
    const int kt = is_type ? (bid % 12) : (bid - 96);
    const int k0 = kt * 64;
    const int n0 = is_type ? (bid / 12) * 64 : 0;
    const int ld = is_type ? 500 : 64;
    const int nlim = is_type ? 500 : 64;
    const float* src = is_type ? Wtype : W1;
    unsigned short* dst = is_type ? wt_type : wt_all;
    const int n = t & 63;
    #pragma unroll
    for (int i = 0; i < 16; ++i) {
      int k = i * 4 + (t >> 6);
      tl[k][n] = (n0 + n < nlim) ? src[(size_t)(k0 + k) * ld + n0 + n] : 0.f;
    }
    __syncthreads();
    const int k = t & 63;
    #pragma unroll
    for (int i = 0; i < 16; ++i) {
      int nn = i * 4 + (t >> 6);
      dst[(size_t)(n0 + nn) * 768 + k0 + k] = f2bf(tl[k][nn]);
    }
  } else if (bid == 108) {
    for (int idx = t; idx < 16 * 768; idx += 256) {
      int n = 64 + idx / 768, k = idx % 768;
      float v = (n < 67) ? Wpos[k * 3 + (n - 64)] : 0.f;
      wt_all[(size_t)n * 768 + k] = f2bf(v);
    }
  } else if (bid == 109) {
    int* part = (int*)smem;
    int bb = t >> 2, qq = t & 3;
    const int4* mp = (const int4*)(amask + bb * 512 + qq * 128);
    int s = 0;
    #pragma unroll 8
    for (int i = 0; i < 32; ++i) { int4 v = mp[i]; s += v.x + v.y + v.z + v.w; }
    part[t] = s;
    __syncthreads();
    if (qq == 0) lengths[bb] = part[t] + part[t + 1] + part[t + 2] + part[t + 3];
  }
  __threadfence();
  grid.sync();
  __threadfence();

  // ================= P1: k1 GEMM (all 512 blocks, 64 rows each) =================
  {
    uint4 (*As)[512] = (uint4(*)[512])smem;
    uint4 (*Bs)[512] = (uint4(*)[512])(smem + 32768);
    const int row0 = bid * 64;
    const int c16 = l & 15, q = l >> 4;

    f32x4 acc[5];
    #pragma unroll
    for (int nt = 0; nt < 5; ++nt) acc[nt] = (f32x4){0.f, 0.f, 0.f, 0.f};

    auto stage = [&](int it) {
      const int bi = it & 3;
      const int k0 = it * 32;
      #pragma unroll
      for (int u = 0; u < 2; ++u) {
        int i = w * 128 + u * 64 + l;
        int row = i >> 3;
        int ss = (i & 7) ^ (row & 7);
        gload_lds16(hidden + (size_t)(row0 + row) * 768 + k0 + 4 * ss,
                    (void*)(As[bi] + (w * 128 + u * 64)));
      }
      #pragma unroll
      for (int u = 0; u < 2; ++u) {
        int i = w * 128 + u * 64 + l;
        int row = i >> 2;
        int ss = (i & 3) ^ ((row >> 1) & 3);
        gload_lds16(wt_all + (size_t)row * 768 + k0 + 8 * ss,
                    (void*)(Bs[bi] + (w * 128 + u * 64)));
      }
    };

    stage(0); stage(1);
    for (int it = 0; it < 24; ++it) {
      if (it < 22) stage(it + 2);
      if (it < 22)       asm volatile("s_waitcnt vmcnt(8)" ::: "memory");
      else if (it == 22) asm volatile("s_waitcnt vmcnt(4)" ::: "memory");
      else               asm volatile("s_waitcnt vmcnt(0)" ::: "memory");
      __builtin_amdgcn_s_barrier();
      __builtin_amdgcn_sched_barrier(0);

      const int bi = it & 3;
      const char* Ab = (const char*)As[bi];
      const char* Bb = (const char*)Bs[bi];
      const int arow = 16 * w + c16, r7 = arow & 7;
      float4 alo = *(const float4*)(Ab + arow * 128 + (((2 * q + 0) ^ r7) << 4));
      float4 ahi = *(const float4*)(Ab + arow * 128 + (((2 * q + 1) ^ r7) << 4));
      bf16x8 a = pack8(alo, ahi);
      #pragma unroll
      for (int nt = 0; nt < 5; ++nt) {
        const int brow = 16 * nt + c16;
        bf16x8 b = *(const bf16x8*)(Bb + brow * 64 + ((q ^ ((brow >> 1) & 3)) << 4));
        acc[nt] = __builtin_amdgcn_mfma_f32_16x16x32_bf16(a, b, acc[nt], 0, 0, 0);
      }
    }

    const float bias2 = b2[0];
    #pragma unroll
    for (int r = 0; r < 4; ++r) {
      float s = 0.f;
      #pragma unroll
      for (int nt = 0; nt < 4; ++nt) {
        int c = 16 * nt + c16;
        float x = acc[nt][r] + b1[c];
        float th = 1.f - 2.f / (1.f + exp2f(x * (2.f * L2E)));
        s += th * W2[c];
      }
      #pragma unroll
      for (int off = 1; off < 16; off <<= 1) s += __shfl_xor(s, off, 64);
      if (c16 == 0) {
        int row = row0 + 16 * w + 4 * q + r;
        scores[row] = s + bias2;
      }
    }
    if (c16 < 3) {
      const float bi = biw[0];
      #pragma unroll
      for (int r = 0; r < 4; ++r) {
        int row = row0 + 16 * w + 4 * q + r;
        int bb = row >> 9, ss = row & 511;
        int lab = plab[row];
        float wgt = (lab > 0) ? 1.f + bi : 1.f;
        float ev = (acc[4][r] + bpos[c16]) * wgt;
        em_t[(ss * 3 + c16) * 64 + bb] = ev;
        if (c16 == 0) labels_t[ss * 64 + bb] = lab;
      }
    }
  }
  __threadfence();
  grid.sync();
  __threadfence();

  // ================= P2: kd (bid<256) || k2a (bid 448..463) =================
  if (bid >= 448 && bid < 464) {
    const int b = l, c = (bid - 448) * 4 + w;
    float T0 = trans[0], T1 = trans[1], T2 = trans[2];
    float T3 = trans[3], T4 = trans[4], T5 = trans[5];
    float T6 = trans[6], T7 = trans[7], T8 = trans[8];
    const int L = lengths[b];
    const int s0 = 8 * c;
    int labp = labels_t[(c ? (s0 - 1) : 0) * 64 + b];

    float E0[8], E1[8], E2[8]; int LB[8];
    #pragma unroll
    for (int i = 0; i < 8; ++i) {
      E0[i] = em_t[((s0 + i) * 3 + 0) * 64 + b];
      E1[i] = em_t[((s0 + i) * 3 + 1) * 64 + b];
      E2[i] = em_t[((s0 + i) * 3 + 2) * 64 + b];
      LB[i] = labels_t[(s0 + i) * 64 + b];
    }
    float M[9];
    #pragma unroll
    for (int i = 0; i < 9; ++i) M[i] = (i == 0 || i == 4 || i == 8) ? 0.f : NEGB;
    float sc = 0.f;
    #pragma unroll
    for (int i = 0; i < 8; ++i) {
      int s = s0 + i;
      bool act = (s >= 1) && (s < L);
      float N[9];
      #pragma unroll
      for (int r = 0; r < 3; ++r) {
        float ma = M[3 * r], mb = M[3 * r + 1], mc = M[3 * r + 2];
        N[3 * r + 0] = lse3(ma + T0, mb + T3, mc + T6) + E0[i];
        N[3 * r + 1] = lse3(ma + T1, mb + T4, mc + T7) + E1[i];
        N[3 * r + 2] = lse3(ma + T2, mb + T5, mc + T8) + E2[i];
      }
      #pragma unroll
      for (int r = 0; r < 9; ++r) M[r] = act ? N[r] : M[r];
      int lab = LB[i];
      float ev = sel3(E0[i], E1[i], E2[i], lab);
      float trv = sel3(sel3(T0, T1, T2, lab),
                       sel3(T3, T4, T5, lab),
                       sel3(T6, T7, T8, lab), labp);
      sc += act ? (ev + trv) : 0.f;
      labp = lab;
    }
    #pragma unroll
    for (int i = 0; i < 9; ++i) matM[(c * 9 + i) * 64 + b] = M[i];
    psc[c * 64 + b] = sc;
  } else if (bid < 256) {
    // kd quarter: batch b = bid>>2, cols [128*qt, 128*qt+128)
    unsigned short (*Apool)[776] = (unsigned short(*)[776])smem;       // 12416 B
    float (*logitsL)[132] = (float(*)[132])(smem + 12544);             // 4224 B
    const int b = bid >> 2, qt = bid & 3;

    { // pool 8 spans (32 threads each)
      const int sp = t >> 5;
      const int span = b * 8 + sp;
      const int st = tpos[span * 2], en = tpos[span * 2 + 1];
      const int len = (st + en > 0) ? (en - st) : 0;
      float sv[7], aw[7];
      float wm = -1e30f;
      #pragma unroll
      for (int j = 0; j < 7; ++j) {
        sv[j] = (j < len) ? scores[b * 512 + st + j] : -1e30f;
        wm = fmaxf(wm, sv[j]);
      }
      float den = 0.f;
      #pragma unroll
      for (int j = 0; j < 7; ++j) {
        aw[j] = (j < len) ? exp2f((sv[j] - wm) * L2E) : 0.f;
        den += aw[j];
      }
      float inv = (den > 0.f) ? 1.f / den : 0.f;
      #pragma unroll
      for (int j = 0; j < 7; ++j) aw[j] *= inv;

      const int h0 = (t & 31) * 24;
      float ap[24];
      #pragma unroll
      for (int i = 0; i < 24; ++i) ap[i] = 0.f;
      #pragma unroll
      for (int j = 0; j < 7; ++j) {
        if (j < len) {
          const float4* hp = (const float4*)(hidden + (size_t)(b * 512 + st + j) * 768 + h0);
          #pragma unroll
          for (int i = 0; i < 6; ++i) {
            float4 v = hp[i];
            ap[4 * i + 0] += aw[j] * v.x; ap[4 * i + 1] += aw[j] * v.y;
            ap[4 * i + 2] += aw[j] * v.z; ap[4 * i + 3] += aw[j] * v.w;
          }
        }
      }
      unsigned short* dp = &Apool[sp][h0];
      #pragma unroll
      for (int g = 0; g < 3; ++g) {
        uint4 v;
        v.x = (unsigned)f2bf(ap[8 * g + 0]) | ((unsigned)f2bf(ap[8 * g + 1]) << 16);
        v.y = (unsigned)f2bf(ap[8 * g + 2]) | ((unsigned)f2bf(ap[8 * g + 3]) << 16);
        v.z = (unsigned)f2bf(ap[8 * g + 4]) | ((unsigned)f2bf(ap[8 * g + 5]) << 16);
        v.w = (unsigned)f2bf(ap[8 * g + 6]) | ((unsigned)f2bf(ap[8 * g + 7]) << 16);
        *(uint4*)(dp + 8 * g) = v;
      }
    }
    __syncthreads();

    // GEMM: wave w -> local cols [32w, 32w+32); global col = 128*qt + lc
    const int c16 = l & 15, q = l >> 4;
    const bf16x8 zerov = (bf16x8)(__bf16)0.f;
    const unsigned short* bp0 = wt_type + (size_t)(128 * qt + 32 * w + c16) * 768 + 8 * q;
    const unsigned short* bp1 = bp0 + (size_t)16 * 768;
    f32x4 acc0 = (f32x4){0.f, 0.f, 0.f, 0.f};
    f32x4 acc1 = (f32x4){0.f, 0.f, 0.f, 0.f};
    bf16x8 bc0 = *(const bf16x8*)(bp0);
    bf16x8 bc1 = *(const bf16x8*)(bp1);
    for (int ks = 0; ks < 24; ++ks) {
      bf16x8 bn0, bn1;
      if (ks < 23) {
        bn0 = *(const bf16x8*)(bp0 + (ks + 1) * 32);
        bn1 = *(const bf16x8*)(bp1 + (ks + 1) * 32);
      }
      bf16x8 a = (c16 < 8) ? *(const bf16x8*)(&Apool[c16][ks * 32 + 8 * q]) : zerov;
      acc0 = __builtin_amdgcn_mfma_f32_16x16x32_bf16(a, bc0, acc0, 0, 0, 0);
      acc1 = __builtin_amdgcn_mfma_f32_16x16x32_bf16(a, bc1, acc1, 0, 0, 0);
      if (ks < 23) { bc0 = bn0; bc1 = bn1; }
    }
    if (q < 2) {
      #pragma unroll
      for (int r = 0; r < 4; ++r) {
        logitsL[4 * q + r][32 * w + c16] = acc0[r];
        logitsL[4 * q + r][32 * w + 16 + c16] = acc1[r];
      }
    }
    __syncthreads();

    // partial softmax stats per row over this quarter's 128 cols
    #pragma unroll
    for (int rr = 0; rr < 2; ++rr) {
      const int row = 2 * w + rr;
      int lc1 = l + 64;
      int gc0 = 128 * qt + l, gc1 = 128 * qt + lc1;
      bool v1 = gc1 < 500;
      float lv0 = logitsL[row][l] + btype[gc0];          // gc0 always < 500
      float lv1 = v1 ? logitsL[row][lc1] + btype[gc1] : -1e30f;
      float m = fmaxf(lv0, lv1);
      #pragma unroll
      for (int off = 1; off < 64; off <<= 1) m = fmaxf(m, __shfl_xor(m, off, 64));
      float se = exp2f((lv0 - m) * L2E) + exp2f((lv1 - m) * L2E);
      float ss = lv0 + (v1 ? lv1 : 0.f);
      #pragma unroll
      for (int off = 1; off < 64; off <<= 1) {
        se += __shfl_xor(se, off, 64);
        ss += __shfl_xor(ss, off, 64);
      }
      if (l == 0) {
        float* dst = pq + ((size_t)(b * 8 + row) * 4 + qt) * 4;
        dst[0] = m; dst[1] = se; dst[2] = ss;
        int lbl = tlab[b * 8 + row];
        if ((lbl >> 7) == qt)
          vlbuf[b * 8 + row] = logitsL[row][lbl - 128 * qt] + btype[lbl];
      }
    }
  }
  __threadfence();
  grid.sync();
  __threadfence();

  // ================= P3: block 0 — focal combine + CRF scan + output =================
  if (bid == 0) {
    float* red = (float*)smem;
    float fsum = 0.f, vsum = 0.f;
    #pragma unroll
    for (int rr = 0; rr < 2; ++rr) {
      int row = 2 * t + rr;
      const float* p0 = pq + (size_t)row * 16;
      float m0 = p0[0], m1 = p0[4], m2 = p0[8], m3 = p0[12];
      float gm = fmaxf(fmaxf(m0, m1), fmaxf(m2, m3));
      float se = p0[1] * exp2f((m0 - gm) * L2E) + p0[5] * exp2f((m1 - gm) * L2E)
               + p0[9] * exp2f((m2 - gm) * L2E) + p0[13] * exp2f((m3 - gm) * L2E);
      float ss = p0[2] + p0[6] + p0[10] + p0[14];
      float logZ = gm + log2f(se) * LN2;
      float lp = vlbuf[row] - logZ;
      float ce = -(0.9f * lp + 2e-4f * (ss - 500.f * logZ));
      float pt = 0.9f * exp2f(lp * L2E) + 2e-4f;
      float focal = ce * (1.f - pt) * (1.f - pt);
      bool valid = (tpos[row * 2] + tpos[row * 2 + 1]) > 0;
      fsum += valid ? focal : 0.f;
      vsum += valid ? 1.f : 0.f;
    }
    #pragma unroll
    for (int off = 1; off < 64; off <<= 1) {
      fsum += __shfl_xor(fsum, off, 64);
      vsum += __shfl_xor(vsum, off, 64);
    }
    if (l == 0) { red[w * 2] = fsum; red[w * 2 + 1] = vsum; }
    __syncthreads();
    if (t == 0) {
      red[8] = red[0] + red[2] + red[4] + red[6];
      red[9] = red[1] + red[3] + red[5] + red[7];
    }
    __syncthreads();

    if (t < 64) {
      const int b = t;
      const int L = lengths[b];
      const float st0 = strans[0], st1 = strans[1], st2 = strans[2];
      const float et0 = etrans[0], et1 = etrans[1], et2 = etrans[2];
      float e00 = em_t[0 * 64 + b], e01 = em_t[1 * 64 + b], e02 = em_t[2 * 64 + b];
      int lab0 = labels_t[b];
      float a0 = st0 + e00, a1 = st1 + e01, a2 = st2 + e02;
      float score = sel3(st0, st1, st2, lab0) + sel3(e00, e01, e02, lab0);

      float cur[4][10];
      #pragma unroll
      for (int j = 0; j < 4; ++j) {
        #pragma unroll
        for (int i = 0; i < 9; ++i) cur[j][i] = matM[(j * 9 + i) * 64 + b];
        cur[j][9] = psc[j * 64 + b];
      }
      for (int r = 0; r < 16; ++r) {
        float nxt[4][10];
        if (r < 15) {
          #pragma unroll
          for (int j = 0; j < 4; ++j) {
            int c = (r + 1) * 4 + j;
            #pragma unroll
            for (int i = 0; i < 9; ++i) nxt[j][i] = matM[(c * 9 + i) * 64 + b];
            nxt[j][9] = psc[c * 64 + b];
          }
        }
        #pragma unroll
        for (int j = 0; j < 4; ++j) {
          float n0 = lse3(a0 + cur[j][0], a1 + cur[j][3], a2 + cur[j][6]);
          float n1 = lse3(a0 + cur[j][1], a1 + cur[j][4], a2 + cur[j][7]);
          float n2 = lse3(a0 + cur[j][2], a1 + cur[j][5], a2 + cur[j][8]);
          a0 = n0; a1 = n1; a2 = n2;
          score += cur[j][9];
        }
        if (r < 15) {
          #pragma unroll
          for (int j = 0; j < 4; ++j)
            #pragma unroll
            for (int i = 0; i < 10; ++i) cur[j][i] = nxt[j][i];
        }
      }
      int last = labels_t[(L - 1) * 64 + b];
      score += sel3(et0, et1, et2, last);
      float logZ = lse3(a0 + et0, a1 + et1, a2 + et2);
      float nll = logZ - score;
      #pragma unroll
      for (int off = 1; off < 64; off <<= 1) nll += __shfl_xor(nll, off, 64);
      if (b == 0) {
        float pos = nll / 64.f;
        float type = red[8] / fmaxf(red[9], 1.f) * 10.f;
        out[0] = 0.6f * pos + 0.4f * type;
        out[1] = pos;
        out[2] = type;
      }
    }
  }
}

extern "C" void kernel_launch(void* const* d_in, const int* in_sizes, int n_in,
                              void* d_out, int out_size, void* d_ws, size_t ws_size,
                              hipStream_t stream) {
  const float* hidden = (const float*)d_in[0];
  const int*   amask  = (const int*)d_in[1];
  const int*   plab   = (const int*)d_in[2];
  const int*   tlab   = (const int*)d_in[3];
  const int*   tpos   = (const int*)d_in[4];
  const float* biw    = (const float*)d_in[5];
  const float* Wpos   = (const float*)d_in[6];
  const float* bpos   = (const float*)d_in[7];
  const float* strans = (const float*)d_in[8];
  const float* etrans = (const float*)d_in[9];
  const float* trans  = (const float*)d_in[10];
  const float* W1     = (const float*)d_in[11];
  const float* b1     = (const float*)d_in[12];
  const float* W2     = (const float*)d_in[13];
  const float* b2     = (const float*)d_in[14];
  const float* Wtype  = (const float*)d_in[15];
  const float* btype  = (const float*)d_in[16];
  char* ws = (char*)d_ws;
  float* out = (float*)d_out;

  void* args[] = {
    (void*)&hidden, (void*)&amask, (void*)&plab, (void*)&tlab, (void*)&tpos,
    (void*)&biw, (void*)&Wpos, (void*)&bpos, (void*)&strans, (void*)&etrans,
    (void*)&trans, (void*)&W1, (void*)&b1, (void*)&W2, (void*)&b2,
    (void*)&Wtype, (void*)&btype, (void*)&ws, (void*)&out };
  hipLaunchCooperativeKernel((const void*)mega, dim3(512), dim3(256), args, 0, stream);
}

// Round 11
// 85.830 us; speedup vs baseline: 5.5951x; 5.5951x over previous
//
#include <hip/hip_runtime.h>

#define L2E 1.44269504088896340736f
#define LN2 0.69314718055994530942f
#define NEGB -1e30f

typedef float f32x4 __attribute__((ext_vector_type(4)));
typedef __bf16 bf16x8 __attribute__((ext_vector_type(8)));

// workspace layout (bytes)
static constexpr size_t WT_ALL_OFF   = 0;        // 80*768 bf16
static constexpr size_t WT_TYPE_OFF  = 122880;   // 512*768 bf16 (rows 500..511 zero)
static constexpr size_t EM_T_OFF     = 909312;   // 512*3*64 f32 (em_t[s][j][b])
static constexpr size_t SCORES_OFF   = 1302528;  // 64*512 f32
static constexpr size_t LABELS_T_OFF = 1433600;  // 512*64 i32
static constexpr size_t LEN_OFF      = 1564672;  // 64 i32
static constexpr size_t POOLED_OFF   = 2351360;  // 512*768 bf16
static constexpr size_t MATM_OFF     = 3400192;  // 64*9*64 f32
static constexpr size_t PSC_OFF      = 3547648;  // 64*64 f32
static constexpr size_t PQ_OFF       = 3564032;  // 512 rows * 8 octs * 4 f32 = 65536
static constexpr size_t VL_OFF       = 3629568;  // 512 f32

__device__ __forceinline__ unsigned short f2bf(float f) {
  unsigned u = __builtin_bit_cast(unsigned, f);
  u += 0x7FFFu + ((u >> 16) & 1u);
  return (unsigned short)(u >> 16);
}
__device__ __forceinline__ float sel3(float a, float b, float c, int i) {
  return i == 0 ? a : (i == 1 ? b : c);
}
__device__ __forceinline__ float lse3(float x, float y, float z) {
  float m = fmaxf(fmaxf(x, y), z);
  float p = exp2f((x - m) * L2E) + exp2f((y - m) * L2E) + exp2f((z - m) * L2E);
  return m + log2f(p) * LN2;
}
__device__ __forceinline__ bf16x8 pack8(float4 lo, float4 hi) {
  union { unsigned u[4]; bf16x8 v; } r;
  asm("v_cvt_pk_bf16_f32 %0, %1, %2" : "=v"(r.u[0]) : "v"(lo.x), "v"(lo.y));
  asm("v_cvt_pk_bf16_f32 %0, %1, %2" : "=v"(r.u[1]) : "v"(lo.z), "v"(lo.w));
  asm("v_cvt_pk_bf16_f32 %0, %1, %2" : "=v"(r.u[2]) : "v"(hi.x), "v"(hi.y));
  asm("v_cvt_pk_bf16_f32 %0, %1, %2" : "=v"(r.u[3]) : "v"(hi.z), "v"(hi.w));
  return r.v;
}
__device__ __forceinline__ void gload_lds16(const void* g, void* l) {
  __builtin_amdgcn_global_load_lds(
      (const __attribute__((address_space(1))) unsigned*)g,
      (__attribute__((address_space(3))) unsigned*)l, 16, 0, 0);
}

// ---------------- K_A: coalesced weight transposes + lengths ---------------------------------
__global__ __launch_bounds__(256) void ka_prep(
    const float* __restrict__ W1, const float* __restrict__ Wpos,
    const float* __restrict__ Wtype, const int* __restrict__ amask,
    unsigned short* __restrict__ wt_all, unsigned short* __restrict__ wt_type,
    int* __restrict__ lengths) {
  const int bid = blockIdx.x, t = threadIdx.x;
  if (bid < 108) {
    __shared__ float tl[64][65];
    const bool is_type = bid < 96;
    const int kt = is_type ? (bid % 12) : (bid - 96);
    const int k0 = kt * 64;
    const int n0 = is_type ? (bid / 12) * 64 : 0;
    const int ld = is_type ? 500 : 64;
    const int nlim = is_type ? 500 : 64;
    const float* src = is_type ? Wtype : W1;
    unsigned short* dst = is_type ? wt_type : wt_all;
    const int n = t & 63;
    #pragma unroll
    for (int i = 0; i < 16; ++i) {
      int k = i * 4 + (t >> 6);
      tl[k][n] = (n0 + n < nlim) ? src[(size_t)(k0 + k) * ld + n0 + n] : 0.f;
    }
    __syncthreads();
    const int k = t & 63;
    #pragma unroll
    for (int i = 0; i < 16; ++i) {
      int nn = i * 4 + (t >> 6);
      dst[(size_t)(n0 + nn) * 768 + k0 + k] = f2bf(tl[k][nn]);
    }
  } else if (bid == 108) {
    for (int idx = t; idx < 16 * 768; idx += 256) {
      int n = 64 + idx / 768, k = idx % 768;
      float v = (n < 67) ? Wpos[k * 3 + (n - 64)] : 0.f;
      wt_all[(size_t)n * 768 + k] = f2bf(v);
    }
  } else {
    __shared__ int part[256];
    int bb = t >> 2, qq = t & 3;
    const int4* mp = (const int4*)(amask + bb * 512 + qq * 128);
    int s = 0;
    #pragma unroll 8
    for (int i = 0; i < 32; ++i) { int4 v = mp[i]; s += v.x + v.y + v.z + v.w; }
    part[t] = s;
    __syncthreads();
    if (qq == 0) lengths[bb] = part[t] + part[t + 1] + part[t + 2] + part[t + 3];
  }
}

// ---------------- K1: [32768x768]@[768x80] bf16 MFMA, 4-buf 2-deep DMA pipeline --------------
__global__ __launch_bounds__(256) void k1_gemm(
    const float* __restrict__ hidden, const int* __restrict__ plab,
    const float* __restrict__ bpos, const float* __restrict__ b1,
    const float* __restrict__ W2, const float* __restrict__ b2,
    const float* __restrict__ biw, const unsigned short* __restrict__ wt_all,
    float* __restrict__ em_t, float* __restrict__ scores, int* __restrict__ labels_t) {
  __shared__ uint4 As[4][512];
  __shared__ uint4 Bs[4][512];
  const int t = threadIdx.x, w = t >> 6, l = t & 63;
  const int row0 = blockIdx.x * 64;
  const int c16 = l & 15, q = l >> 4;

  f32x4 acc[5];
  #pragma unroll
  for (int nt = 0; nt < 5; ++nt) acc[nt] = (f32x4){0.f, 0.f, 0.f, 0.f};

  auto stage = [&](int it) {
    const int bi = it & 3;
    const int k0 = it * 32;
    #pragma unroll
    for (int u = 0; u < 2; ++u) {
      int i = w * 128 + u * 64 + l;
      int row = i >> 3;
      int ss = (i & 7) ^ (row & 7);
      gload_lds16(hidden + (size_t)(row0 + row) * 768 + k0 + 4 * ss,
                  (void*)(As[bi] + (w * 128 + u * 64)));
    }
    #pragma unroll
    for (int u = 0; u < 2; ++u) {
      int i = w * 128 + u * 64 + l;
      int row = i >> 2;
      int ss = (i & 3) ^ ((row >> 1) & 3);
      gload_lds16(wt_all + (size_t)row * 768 + k0 + 8 * ss,
                  (void*)(Bs[bi] + (w * 128 + u * 64)));
    }
  };

  stage(0); stage(1);
  for (int it = 0; it < 24; ++it) {
    if (it < 22) stage(it + 2);
    if (it < 22)       asm volatile("s_waitcnt vmcnt(8)" ::: "memory");
    else if (it == 22) asm volatile("s_waitcnt vmcnt(4)" ::: "memory");
    else               asm volatile("s_waitcnt vmcnt(0)" ::: "memory");
    __builtin_amdgcn_s_barrier();
    __builtin_amdgcn_sched_barrier(0);

    const int bi = it & 3;
    const char* Ab = (const char*)As[bi];
    const char* Bb = (const char*)Bs[bi];
    const int arow = 16 * w + c16, r7 = arow & 7;
    float4 alo = *(const float4*)(Ab + arow * 128 + (((2 * q + 0) ^ r7) << 4));
    float4 ahi = *(const float4*)(Ab + arow * 128 + (((2 * q + 1) ^ r7) << 4));
    bf16x8 a = pack8(alo, ahi);
    #pragma unroll
    for (int nt = 0; nt < 5; ++nt) {
      const int brow = 16 * nt + c16;
      bf16x8 b = *(const bf16x8*)(Bb + brow * 64 + ((q ^ ((brow >> 1) & 3)) << 4));
      acc[nt] = __builtin_amdgcn_mfma_f32_16x16x32_bf16(a, b, acc[nt], 0, 0, 0);
    }
  }

  const float bias2 = b2[0];
  #pragma unroll
  for (int r = 0; r < 4; ++r) {
    float s = 0.f;
    #pragma unroll
    for (int nt = 0; nt < 4; ++nt) {
      int c = 16 * nt + c16;
      float x = acc[nt][r] + b1[c];
      float th = 1.f - 2.f / (1.f + exp2f(x * (2.f * L2E)));
      s += th * W2[c];
    }
    #pragma unroll
    for (int off = 1; off < 16; off <<= 1) s += __shfl_xor(s, off, 64);
    if (c16 == 0) {
      int row = row0 + 16 * w + 4 * q + r;
      scores[row] = s + bias2;
    }
  }
  if (c16 < 3) {
    const float bi = biw[0];
    #pragma unroll
    for (int r = 0; r < 4; ++r) {
      int row = row0 + 16 * w + 4 * q + r;
      int bb = row >> 9, ss = row & 511;
      int lab = plab[row];
      float wgt = (lab > 0) ? 1.f + bi : 1.f;
      float ev = (acc[4][r] + bpos[c16]) * wgt;
      em_t[(ss * 3 + c16) * 64 + bb] = ev;
      if (c16 == 0) labels_t[ss * 64 + bb] = lab;
    }
  }
}

// ---------------- KPC: {bid<512: span pooling | bid>=512: CRF chunk matrices} ----------------
__global__ __launch_bounds__(64) void kpc(
    const float* __restrict__ hidden, const float* __restrict__ scores,
    const int* __restrict__ tpos, unsigned short* __restrict__ pooled,
    const float* __restrict__ em_t, const int* __restrict__ labels_t,
    const int* __restrict__ lengths, const float* __restrict__ trans,
    float* __restrict__ matM, float* __restrict__ psc) {
  const int bid = blockIdx.x, l = threadIdx.x;
  if (bid < 512) {
    const int span = bid;
    const int b = span >> 3;
    const int st = tpos[span * 2], en = tpos[span * 2 + 1];
    int len = (st + en > 0) ? (en - st) : 0;
    float sv[7], aw[7];
    float wm = -1e30f;
    #pragma unroll
    for (int j = 0; j < 7; ++j) {
      sv[j] = (j < len) ? scores[b * 512 + st + j] : -1e30f;
      wm = fmaxf(wm, sv[j]);
    }
    float den = 0.f;
    #pragma unroll
    for (int j = 0; j < 7; ++j) {
      aw[j] = (j < len) ? exp2f((sv[j] - wm) * L2E) : 0.f;
      den += aw[j];
    }
    float inv = (den > 0.f) ? 1.f / den : 0.f;
    #pragma unroll
    for (int j = 0; j < 7; ++j) aw[j] *= inv;
    #pragma unroll
    for (int r = 0; r < 12; ++r) {
      int h = l + 64 * r;
      float acc = 0.f;
      #pragma unroll
      for (int j = 0; j < 7; ++j)
        if (j < len) acc += aw[j] * hidden[(size_t)(b * 512 + st + j) * 768 + h];
      pooled[span * 768 + h] = f2bf(acc);
    }
  } else {
    const int b = l, c = bid - 512;
    float T0 = trans[0], T1 = trans[1], T2 = trans[2];
    float T3 = trans[3], T4 = trans[4], T5 = trans[5];
    float T6 = trans[6], T7 = trans[7], T8 = trans[8];
    const int L = lengths[b];
    const int s0 = 8 * c;
    int labp = labels_t[(c ? (s0 - 1) : 0) * 64 + b];

    float E0[8], E1[8], E2[8]; int LB[8];
    #pragma unroll
    for (int i = 0; i < 8; ++i) {
      E0[i] = em_t[((s0 + i) * 3 + 0) * 64 + b];
      E1[i] = em_t[((s0 + i) * 3 + 1) * 64 + b];
      E2[i] = em_t[((s0 + i) * 3 + 2) * 64 + b];
      LB[i] = labels_t[(s0 + i) * 64 + b];
    }
    float M[9];
    #pragma unroll
    for (int i = 0; i < 9; ++i) M[i] = (i == 0 || i == 4 || i == 8) ? 0.f : NEGB;
    float sc = 0.f;
    #pragma unroll
    for (int i = 0; i < 8; ++i) {
      int s = s0 + i;
      bool act = (s >= 1) && (s < L);
      float N[9];
      #pragma unroll
      for (int r = 0; r < 3; ++r) {
        float ma = M[3 * r], mb = M[3 * r + 1], mc = M[3 * r + 2];
        N[3 * r + 0] = lse3(ma + T0, mb + T3, mc + T6) + E0[i];
        N[3 * r + 1] = lse3(ma + T1, mb + T4, mc + T7) + E1[i];
        N[3 * r + 2] = lse3(ma + T2, mb + T5, mc + T8) + E2[i];
      }
      #pragma unroll
      for (int r = 0; r < 9; ++r) M[r] = act ? N[r] : M[r];
      int lab = LB[i];
      float ev = sel3(E0[i], E1[i], E2[i], lab);
      float trv = sel3(sel3(T0, T1, T2, lab),
                       sel3(T3, T4, T5, lab),
                       sel3(T6, T7, T8, lab), labp);
      sc += act ? (ev + trv) : 0.f;
      labp = lab;
    }
    #pragma unroll
    for (int i = 0; i < 9; ++i) matM[(c * 9 + i) * 64 + b] = M[i];
    psc[c * 64 + b] = sc;
  }
}

// ---------------- K_tg2: type-GEMM partials, 512 blocks (b x oct), DMA 6-buf depth-3 ---------
// block (b, oc): rows 8b..8b+8, cols 64oc..64oc+64. Emits per-(row,oct) softmax partials.
__global__ __launch_bounds__(256) void k_tg2(
    const unsigned short* __restrict__ pooled, const unsigned short* __restrict__ wt_type,
    const float* __restrict__ btype, const int* __restrict__ tlab,
    float* __restrict__ pq, float* __restrict__ vlbuf) {
  __shared__ unsigned short Apool[8][776];     // 12416 B
  __shared__ uint4 Bt[6][512];                 // 49152 B
  __shared__ float logitsL[8][68];             // 2176 B
  const int t = threadIdx.x, w = t >> 6, l = t & 63;
  const int b = blockIdx.x >> 3, oc = blockIdx.x & 7;
  const int c16 = l & 15, q = l >> 4;

  // stage A-tile (8 rows x 768 bf16) once: 768 uint4, 3 per thread
  #pragma unroll
  for (int u = 0; u < 3; ++u) {
    int i = u * 256 + t;
    int row = i / 96, c8 = i % 96;
    *(uint4*)(&Apool[row][c8 * 8]) =
        *(const uint4*)(pooled + (size_t)(b * 8 + row) * 768 + c8 * 8);
  }

  auto stageB = [&](int kt) {
    const int bi = kt % 6;
    #pragma unroll
    for (int u = 0; u < 2; ++u) {
      int i = u * 256 + t;                     // slot 0..511
      int row = i >> 3;
      int ss = (i & 7) ^ (row & 7);
      gload_lds16(wt_type + (size_t)(oc * 64 + row) * 768 + kt * 64 + 8 * ss,
                  (void*)(Bt[bi] + i));
    }
  };

  stageB(0); stageB(1); stageB(2);
  f32x4 acc = (f32x4){0.f, 0.f, 0.f, 0.f};
  const bf16x8 zerov = (bf16x8)(__bf16)0.f;
  for (int kt = 0; kt < 12; ++kt) {
    if (kt < 9)        { stageB(kt + 3); asm volatile("s_waitcnt vmcnt(6)" ::: "memory"); }
    else if (kt == 9)  asm volatile("s_waitcnt vmcnt(4)" ::: "memory");
    else if (kt == 10) asm volatile("s_waitcnt vmcnt(2)" ::: "memory");
    else               asm volatile("s_waitcnt vmcnt(0)" ::: "memory");
    __builtin_amdgcn_s_barrier();
    __builtin_amdgcn_sched_barrier(0);

    const char* Bb = (const char*)Bt[kt % 6];
    const int brow = 16 * w + c16, r7 = brow & 7;
    #pragma unroll
    for (int ks = 0; ks < 2; ++ks) {
      bf16x8 a = (c16 < 8) ? *(const bf16x8*)(&Apool[c16][kt * 64 + ks * 32 + 8 * q]) : zerov;
      bf16x8 bb = *(const bf16x8*)(Bb + brow * 128 + (((ks * 4 + q) ^ r7) << 4));
      acc = __builtin_amdgcn_mfma_f32_16x16x32_bf16(a, bb, acc, 0, 0, 0);
    }
  }
  // D: row = 4q + r (valid q<2), local col = 16w + c16
  if (q < 2) {
    #pragma unroll
    for (int r = 0; r < 4; ++r) logitsL[4 * q + r][16 * w + c16] = acc[r];
  }
  __syncthreads();

  // per-row partial stats over this block's 64 cols; wave w -> rows 2w, 2w+1
  #pragma unroll
  for (int rr = 0; rr < 2; ++rr) {
    const int row = 2 * w + rr;
    int gc = 64 * oc + l;
    bool ok = gc < 500;
    float lv = ok ? logitsL[row][l] + btype[gc] : -1e30f;
    float m = lv;
    #pragma unroll
    for (int off = 1; off < 64; off <<= 1) m = fmaxf(m, __shfl_xor(m, off, 64));
    float se = ok ? exp2f((lv - m) * L2E) : 0.f;
    float ss = ok ? lv : 0.f;
    #pragma unroll
    for (int off = 1; off < 64; off <<= 1) {
      se += __shfl_xor(se, off, 64);
      ss += __shfl_xor(ss, off, 64);
    }
    if (l == 0) {
      int grow = b * 8 + row;
      float* dst = pq + ((size_t)grow * 8 + oc) * 4;
      dst[0] = m; dst[1] = se; dst[2] = ss;
      int lbl = tlab[grow];
      if ((lbl >> 6) == oc) vlbuf[grow] = logitsL[row][lbl & 63] + btype[lbl];
    }
  }
}

// ---------------- K_final: focal oct-combine + CRF chunk-scan + output -----------------------
__global__ __launch_bounds__(256) void k_final(
    const float* __restrict__ pq, const float* __restrict__ vlbuf,
    const int* __restrict__ tpos, const float* __restrict__ em_t,
    const int* __restrict__ labels_t, const int* __restrict__ lengths,
    const float* __restrict__ strans, const float* __restrict__ etrans,
    const float* __restrict__ matM, const float* __restrict__ psc,
    float* __restrict__ out) {
  __shared__ float red[16];
  const int t = threadIdx.x, w = t >> 6, l = t & 63;

  float fsum = 0.f, vsum = 0.f;
  #pragma unroll
  for (int rr = 0; rr < 2; ++rr) {
    int row = t + 256 * rr;
    const float* p0 = pq + (size_t)row * 32;
    float gm = -1e30f;
    #pragma unroll
    for (int o = 0; o < 8; ++o) gm = fmaxf(gm, p0[4 * o]);
    float se = 0.f, ss = 0.f;
    #pragma unroll
    for (int o = 0; o < 8; ++o) {
      se += p0[4 * o + 1] * exp2f((p0[4 * o] - gm) * L2E);
      ss += p0[4 * o + 2];
    }
    float logZ = gm + log2f(se) * LN2;
    float lp = vlbuf[row] - logZ;
    float ce = -(0.9f * lp + 2e-4f * (ss - 500.f * logZ));
    float pt = 0.9f * exp2f(lp * L2E) + 2e-4f;
    float focal = ce * (1.f - pt) * (1.f - pt);
    bool valid = (tpos[row * 2] + tpos[row * 2 + 1]) > 0;
    fsum += valid ? focal : 0.f;
    vsum += valid ? 1.f : 0.f;
  }
  #pragma unroll
  for (int off = 1; off < 64; off <<= 1) {
    fsum += __shfl_xor(fsum, off, 64);
    vsum += __shfl_xor(vsum, off, 64);
  }
  if (l == 0) { red[w * 2] = fsum; red[w * 2 + 1] = vsum; }
  __syncthreads();
  if (t == 0) {
    red[8] = red[0] + red[2] + red[4] + red[6];
    red[9] = red[1] + red[3] + red[5] + red[7];
  }
  __syncthreads();

  if (t < 64) {
    const int b = t;
    const int L = lengths[b];
    const float st0 = strans[0], st1 = strans[1], st2 = strans[2];
    const float et0 = etrans[0], et1 = etrans[1], et2 = etrans[2];
    float e00 = em_t[0 * 64 + b], e01 = em_t[1 * 64 + b], e02 = em_t[2 * 64 + b];
    int lab0 = labels_t[b];
    float a0 = st0 + e00, a1 = st1 + e01, a2 = st2 + e02;
    float score = sel3(st0, st1, st2, lab0) + sel3(e00, e01, e02, lab0);

    float cur[4][10];
    #pragma unroll
    for (int j = 0; j < 4; ++j) {
      #pragma unroll
      for (int i = 0; i < 9; ++i) cur[j][i] = matM[(j * 9 + i) * 64 + b];
      cur[j][9] = psc[j * 64 + b];
    }
    for (int r = 0; r < 16; ++r) {
      float nxt[4][10];
      if (r < 15) {
        #pragma unroll
        for (int j = 0; j < 4; ++j) {
          int c = (r + 1) * 4 + j;
          #pragma unroll
          for (int i = 0; i < 9; ++i) nxt[j][i] = matM[(c * 9 + i) * 64 + b];
          nxt[j][9] = psc[c * 64 + b];
        }
      }
      #pragma unroll
      for (int j = 0; j < 4; ++j) {
        float n0 = lse3(a0 + cur[j][0], a1 + cur[j][3], a2 + cur[j][6]);
        float n1 = lse3(a0 + cur[j][1], a1 + cur[j][4], a2 + cur[j][7]);
        float n2 = lse3(a0 + cur[j][2], a1 + cur[j][5], a2 + cur[j][8]);
        a0 = n0; a1 = n1; a2 = n2;
        score += cur[j][9];
      }
      if (r < 15) {
        #pragma unroll
        for (int j = 0; j < 4; ++j)
          #pragma unroll
          for (int i = 0; i < 10; ++i) cur[j][i] = nxt[j][i];
      }
    }
    int last = labels_t[(L - 1) * 64 + b];
    score += sel3(et0, et1, et2, last);
    float logZ = lse3(a0 + et0, a1 + et1, a2 + et2);
    float nll = logZ - score;
    #pragma unroll
    for (int off = 1; off < 64; off <<= 1) nll += __shfl_xor(nll, off, 64);
    if (b == 0) {
      float pos = nll / 64.f;
      float type = red[8] / fmaxf(red[9], 1.f) * 10.f;
      out[0] = 0.6f * pos + 0.4f * type;
      out[1] = pos;
      out[2] = type;
    }
  }
}

extern "C" void kernel_launch(void* const* d_in, const int* in_sizes, int n_in,
                              void* d_out, int out_size, void* d_ws, size_t ws_size,
                              hipStream_t stream) {
  const float* hidden = (const float*)d_in[0];
  const int*   amask  = (const int*)d_in[1];
  const int*   plab   = (const int*)d_in[2];
  const int*   tlab   = (const int*)d_in[3];
  const int*   tpos   = (const int*)d_in[4];
  const float* biw    = (const float*)d_in[5];
  const float* Wpos   = (const float*)d_in[6];
  const float* bpos   = (const float*)d_in[7];
  const float* strans = (const float*)d_in[8];
  const float* etrans = (const float*)d_in[9];
  const float* trans  = (const float*)d_in[10];
  const float* W1     = (const float*)d_in[11];
  const float* b1     = (const float*)d_in[12];
  const float* W2     = (const float*)d_in[13];
  const float* b2     = (const float*)d_in[14];
  const float* Wtype  = (const float*)d_in[15];
  const float* btype  = (const float*)d_in[16];
  float* out = (float*)d_out;
  char* ws = (char*)d_ws;

  unsigned short* wt_all  = (unsigned short*)(ws + WT_ALL_OFF);
  unsigned short* wt_type = (unsigned short*)(ws + WT_TYPE_OFF);
  float* em_t    = (float*)(ws + EM_T_OFF);
  float* scores  = (float*)(ws + SCORES_OFF);
  int*   labelsT = (int*)(ws + LABELS_T_OFF);
  int*   lengths = (int*)(ws + LEN_OFF);
  unsigned short* pooled = (unsigned short*)(ws + POOLED_OFF);
  float* matM    = (float*)(ws + MATM_OFF);
  float* psc     = (float*)(ws + PSC_OFF);
  float* pq      = (float*)(ws + PQ_OFF);
  float* vlbuf   = (float*)(ws + VL_OFF);

  ka_prep<<<110, 256, 0, stream>>>(W1, Wpos, Wtype, amask, wt_all, wt_type, lengths);
  k1_gemm<<<512, 256, 0, stream>>>(hidden, plab, bpos, b1, W2, b2, biw, wt_all,
                                   em_t, scores, labelsT);
  kpc<<<576, 64, 0, stream>>>(hidden, scores, tpos, pooled, em_t, labelsT, lengths,
                              trans, matM, psc);
  k_tg2<<<512, 256, 0, stream>>>(pooled, wt_type, btype, tlab, pq, vlbuf);
  k_final<<<1, 256, 0, stream>>>(pq, vlbuf, tpos, em_t, labelsT, lengths,
                                 strans, etrans, matM, psc, out);
}